// Round 17
// baseline (273.244 us; speedup 1.0000x reference)
//
#include <hip/hip_runtime.h>
#include <math.h>

#define N_TOTAL   32768
#define K_ENT     4096
#define DIM       64
#define BMR       128
#define BK        128
#define CAPG      32
#define EPS       1.0f
#define BIAS      256.0f

typedef __attribute__((ext_vector_type(4))) float f32x4;
typedef __attribute__((ext_vector_type(8))) short bf16x8;
typedef __attribute__((ext_vector_type(4))) unsigned short u16x4;

// ws layout (float offsets) — total ~4.9 MB
#define WS_NCB    0            // 4096 floats: BIAS - 0.5*||w_k||^2
#define WS_WHI    4096         // 4096x64 ushort hi-plane (512 KB)
#define WS_CNT    135168       // 32768 ints: per-row candidate count
#define WS_CAND   167936       // 32768 x CAPG ints: candidate lists (4 MB)
// out layout (fp32 element offsets)
#define OUT_ZQ    0
#define OUT_IDX   2097152
#define OUT_LOSS  2129920
#define OUT_ENC   2134016
#define OUT_EMB   2138112

#define NEG_BIG   -3.0e38f

// inline-asm 16B load + counted waits (r15 machinery), fenced per rule #18.
#define GLOAD(dst, ptr) \
  asm volatile("global_load_dwordx4 %0, %1, off" : "=&v"(dst) : "v"(ptr))
#define VMWAIT(n) asm volatile("s_waitcnt vmcnt(" #n ")")
#define SB0() __builtin_amdgcn_sched_barrier(0)

__device__ __forceinline__ unsigned short f2bf(float f) {  // RNE
  unsigned int b = __float_as_uint(f);
  return (unsigned short)((b + 0x7fffu + ((b >> 16) & 1u)) >> 16);
}

__global__ __launch_bounds__(256) void prep_kernel(
    const float* __restrict__ w, unsigned short* __restrict__ whi,
    float* __restrict__ ncb) {
  int i = blockIdx.x * 256 + threadIdx.x;      // float4 unit, 0..65535
  float4 v = ((const float4*)w)[i];
  u16x4 h;
  h[0] = f2bf(v.x); h[1] = f2bf(v.y); h[2] = f2bf(v.z); h[3] = f2bf(v.w);
  ((u16x4*)whi)[i] = h;
  float s = fmaf(v.x, v.x, fmaf(v.y, v.y, fmaf(v.z, v.z, v.w * v.w)));
  s += __shfl_xor(s, 1); s += __shfl_xor(s, 2);
  s += __shfl_xor(s, 4); s += __shfl_xor(s, 8);
  if ((threadIdx.x & 15) == 0) ncb[i >> 4] = BIAS - 0.5f * s;
}

// SINGLE-PASS sweep+collect. Block = 128 rows x half of K (grid 512).
// Swapped operands (A=w, B=z). All 4 waves share a per-row running max in
// LDS (thrS, float-as-uint, biased positive). Per chunk: each lane
// atomicMax-es its 8-entry chunk-max into its row slot (return value used),
// then collects entries >= max(old, own) - EPS into global per-row lists.
// Threshold only grows => every entry within EPS of the FINAL row max is
// always collected, for any wave timing => true argmax always in the set.
// Candidate SET varies run-to-run but the fp64-rescored WINNER does not.
__global__ __launch_bounds__(256, 2) void sweep_kernel(
    const float* __restrict__ z, const unsigned short* __restrict__ whi,
    const float* __restrict__ ncb, int* __restrict__ cnt,
    int* __restrict__ cand) {
  __shared__ unsigned int thrS[BMR];
  const int tid = threadIdx.x;
  const int n0  = (blockIdx.x >> 1) * BMR;
  const int khalf = blockIdx.x & 1;
  const int st  = blockIdx.x & 15;
  const int wv  = tid >> 6;
  const int ln  = tid & 63;
  const int g   = ln >> 4;
  const int lm  = ln & 15;
  const int estripe = wv * 32;

  if (tid < BMR) thrS[tid] = 0u;     // below any biased score (~[170,300])

  bf16x8 bz[8][2];
  #pragma unroll
  for (int rt = 0; rt < 8; ++rt) {
    const float* zr = z + (size_t)(n0 + rt * 16 + lm) * DIM;
    #pragma unroll
    for (int s = 0; s < 2; ++s) {
      float4 f0 = *(const float4*)(zr + s * 32 + g * 8);
      float4 f1 = *(const float4*)(zr + s * 32 + g * 8 + 4);
      float ff[8] = {f0.x, f0.y, f0.z, f0.w, f1.x, f1.y, f1.z, f1.w};
      bf16x8 h;
      #pragma unroll
      for (int i = 0; i < 8; ++i) h[i] = (short)f2bf(ff[i]);
      bz[rt][s] = h;
    }
  }
  __syncthreads();                   // thrS initialized

  bf16x8 awA[2][2], awB[2][2];
  f32x4  ncA[2], ncB[2];

  auto chunkbase = [&](int i) { return (khalf * 16 + ((i + st) & 15)) * BK; };
  auto loadW = [&](int kcb, bf16x8 (&aw)[2][2], f32x4 (&nc)[2]) {
    #pragma unroll
    for (int et = 0; et < 2; ++et) {
      const int ebase = kcb + estripe + et * 16;
      const unsigned short* wr = whi + (size_t)(ebase + lm) * DIM + g * 8;
      GLOAD(aw[et][0], wr);
      GLOAD(aw[et][1], wr + 32);
      GLOAD(nc[et], ncb + ebase + g * 4);
    }
  };
  auto comp = [&](int kcb, const bf16x8 (&aw)[2][2], const f32x4 (&nc)[2]) {
    f32x4 acc[2][8];
    #pragma unroll
    for (int et = 0; et < 2; ++et)
      #pragma unroll
      for (int rt = 0; rt < 8; ++rt)
        acc[et][rt] = (f32x4){nc[et][0], nc[et][1], nc[et][2], nc[et][3]};
    #pragma unroll
    for (int et = 0; et < 2; ++et)
      #pragma unroll
      for (int s = 0; s < 2; ++s)
        #pragma unroll
        for (int rt = 0; rt < 8; ++rt)
          acc[et][rt] = __builtin_amdgcn_mfma_f32_16x16x32_bf16(
              aw[et][s], bz[rt][s], acc[et][rt], 0, 0, 0);
    // phase A: chunk-max per row-slot
    float cm[8];
    #pragma unroll
    for (int rt = 0; rt < 8; ++rt)
      cm[rt] = fmaxf(
          fmaxf(fmaxf(acc[0][rt][0], acc[0][rt][1]),
                fmaxf(acc[0][rt][2], acc[0][rt][3])),
          fmaxf(fmaxf(acc[1][rt][0], acc[1][rt][1]),
                fmaxf(acc[1][rt][2], acc[1][rt][3])));
    // phase B: shared running max update (returns pre-update value)
    unsigned int oldv[8];
    #pragma unroll
    for (int rt = 0; rt < 8; ++rt)
      oldv[rt] = atomicMax(&thrS[rt * 16 + lm], __float_as_uint(cm[rt]));
    // phase C: collect vs max(old, own) - EPS
    #pragma unroll
    for (int rt = 0; rt < 8; ++rt) {
      const float thr = fmaxf(__uint_as_float(oldv[rt]), cm[rt]) - EPS;
      if (__builtin_expect(cm[rt] >= thr, 0)) {
        const int rown = n0 + rt * 16 + lm;
        #pragma unroll
        for (int et = 0; et < 2; ++et)
          #pragma unroll
          for (int j = 0; j < 4; ++j) {
            if (acc[et][rt][j] >= thr) {
              int e = kcb + estripe + et * 16 + g * 4 + j;
              int p = atomicAdd(&cnt[rown], 1);
              if (p < CAPG) cand[rown * CAPG + p] = e;
            }
          }
      }
    }
  };

  loadW(chunkbase(0), awA, ncA);
  #pragma unroll 1
  for (int i = 0; i < 16; i += 2) {
    loadW(chunkbase(i + 1), awB, ncB);
    VMWAIT(6); SB0();
    comp(chunkbase(i), awA, ncA);
    if (i + 2 < 16) {
      loadW(chunkbase(i + 2), awA, ncA);
      VMWAIT(6);
    } else {
      VMWAIT(0);
    }
    SB0();
    comp(chunkbase(i + 1), awB, ncB);
  }
}

// Exact fp64 rescore (lane-per-candidate, CAPG<=64) + gather/loss/scatter.
__global__ __launch_bounds__(512) void rescore_gather_kernel(
    const float* __restrict__ z, const float* __restrict__ w,
    const int* __restrict__ cnt, const int* __restrict__ cand,
    float* __restrict__ out_idx, float* __restrict__ out_zq,
    float* __restrict__ out_loss, float* __restrict__ enc,
    float* __restrict__ emb) {
  const int bs = blockIdx.x;
  const int tid = threadIdx.x;
  const int h = tid >> 6, d = tid & 63;
  const int n = bs * 8 + h;

  int nn = cnt[n];
  double bl = -1.0e300;
  int wl = 0x7fffffff;
  if (nn <= CAPG) {
    if (d < nn) {                       // lane d rescores candidate d
      int c = cand[n * CAPG + d];
      double td = 0.0, ud = 0.0;
      #pragma unroll 8
      for (int d2 = 0; d2 < DIM; ++d2) {
        double wv = (double)w[(size_t)c * DIM + d2];
        double zv = (double)z[(size_t)n * DIM + d2];
        td = fma(zv, wv, td);
        ud = fma(wv, wv, ud);
      }
      bl = 2.0 * td - ud;
      wl = c;
    }
  } else {                              // overflow: full exact scan (rare)
    for (int t = 0; t < 64; ++t) {
      int c = t * 64 + d;
      double td = 0.0, ud = 0.0;
      for (int d2 = 0; d2 < DIM; ++d2) {
        double wv = (double)w[(size_t)c * DIM + d2];
        double zv = (double)z[(size_t)n * DIM + d2];
        td = fma(zv, wv, td);
        ud = fma(wv, wv, ud);
      }
      double sd = 2.0 * td - ud;
      if (sd > bl || (sd == bl && c < wl)) { bl = sd; wl = c; }
    }
  }
  #pragma unroll
  for (int mk = 1; mk <= 32; mk <<= 1) {
    double os = __shfl_xor(bl, mk);
    int   oi = __shfl_xor(wl, mk);
    if (os > bl || (os == bl && oi < wl)) { bl = os; wl = oi; }
  }
  int k = wl;
  k = (k < 0) ? 0 : ((k > K_ENT - 1) ? (K_ENT - 1) : k);  // safety clamp
  if (d == 0) out_idx[n] = (float)k;

  const float zf = z[(size_t)n * DIM + d];
  float wvf = w[(size_t)k * DIM + d];
  float stv = zf + (wvf - zf);              // straight-through, ref fp order
  out_zq[(size_t)n * DIM + d] = stv;
  float diff = zf - wvf;
  float s = diff * diff;
  #pragma unroll
  for (int mm = 32; mm >= 1; mm >>= 1) s += __shfl_down(s, mm, 64);
  __shared__ float red[8];
  if ((tid & 63) == 0) red[tid >> 6] = s;
  __syncthreads();
  if (tid == 0) {
    float t = 0.f;
    #pragma unroll
    for (int i = 0; i < 8; ++i) t += red[i];
    out_loss[bs] = t * (1.0f / 512.0f);
  }
  atomicAdd(&emb[(size_t)k * DIM + d], zf);
  if (d == 0) atomicAdd(&enc[k], 1.0f);
}

extern "C" void kernel_launch(void* const* d_in, const int* in_sizes, int n_in,
                              void* d_out, int out_size, void* d_ws, size_t ws_size,
                              hipStream_t stream) {
  const float* z = (const float*)d_in[0];
  const float* w = (const float*)d_in[1];
  float* ws  = (float*)d_ws;
  float* ncb = ws + WS_NCB;
  unsigned short* whi = (unsigned short*)(ws + WS_WHI);
  int* cnt  = (int*)(ws + WS_CNT);
  int* cand = (int*)(ws + WS_CAND);
  float* out = (float*)d_out;

  hipMemsetAsync(out + OUT_ENC, 0, (size_t)(4096 + 262144) * sizeof(float),
                 stream);
  hipMemsetAsync(cnt, 0, (size_t)N_TOTAL * sizeof(int), stream);

  prep_kernel<<<(K_ENT * DIM / 4) / 256, 256, 0, stream>>>(w, whi, ncb);
  sweep_kernel<<<(N_TOTAL / BMR) * 2, 256, 0, stream>>>(z, whi, ncb, cnt,
                                                        cand);
  rescore_gather_kernel<<<N_TOTAL / 8, 512, 0, stream>>>(
      z, w, cnt, cand, out + OUT_IDX, out + OUT_ZQ, out + OUT_LOSS,
      out + OUT_ENC, out + OUT_EMB);
}

// Round 18
// 163.414 us; speedup vs baseline: 1.6721x; 1.6721x over previous
//
#include <hip/hip_runtime.h>
#include <math.h>

#define N_TOTAL   32768
#define K_ENT     4096
#define DIM       64
#define BMR       128
#define BK        128
#define CAPG      32
#define EPS       1.0f
#define BIAS      256.0f

typedef __attribute__((ext_vector_type(4))) float f32x4;
typedef __attribute__((ext_vector_type(8))) short bf16x8;
typedef __attribute__((ext_vector_type(4))) unsigned short u16x4;

// ws layout (float offsets) — total ~4.9 MB
#define WS_NCB    0            // 4096 floats: BIAS - 0.5*||w_k||^2
#define WS_WHI    4096         // 4096x64 ushort hi-plane (512 KB)
#define WS_CNT    135168       // 32768 ints: per-row candidate count
#define WS_CAND   167936       // 32768 x CAPG ints: candidate lists (4 MB)
// out layout (fp32 element offsets)
#define OUT_ZQ    0
#define OUT_IDX   2097152
#define OUT_LOSS  2129920
#define OUT_ENC   2134016
#define OUT_EMB   2138112

#define NEG_BIG   -3.0e38f

// inline-asm 16B load + counted waits (r15 machinery), fenced per rule #18.
#define GLOAD(dst, ptr) \
  asm volatile("global_load_dwordx4 %0, %1, off" : "=&v"(dst) : "v"(ptr))
#define VMWAIT(n) asm volatile("s_waitcnt vmcnt(" #n ")")
#define SB0() __builtin_amdgcn_sched_barrier(0)

__device__ __forceinline__ unsigned short f2bf(float f) {  // RNE
  unsigned int b = __float_as_uint(f);
  return (unsigned short)((b + 0x7fffu + ((b >> 16) & 1u)) >> 16);
}

__global__ __launch_bounds__(256) void prep_kernel(
    const float* __restrict__ w, unsigned short* __restrict__ whi,
    float* __restrict__ ncb) {
  int i = blockIdx.x * 256 + threadIdx.x;      // float4 unit, 0..65535
  float4 v = ((const float4*)w)[i];
  u16x4 h;
  h[0] = f2bf(v.x); h[1] = f2bf(v.y); h[2] = f2bf(v.z); h[3] = f2bf(v.w);
  ((u16x4*)whi)[i] = h;
  float s = fmaf(v.x, v.x, fmaf(v.y, v.y, fmaf(v.z, v.z, v.w * v.w)));
  s += __shfl_xor(s, 1); s += __shfl_xor(s, 2);
  s += __shfl_xor(s, 4); s += __shfl_xor(s, 8);
  if ((threadIdx.x & 15) == 0) ncb[i >> 4] = BIAS - 0.5f * s;
}

// SINGLE-PASS sweep+collect with one-chunk threshold WARM-UP.
// Block = 128 rows x half of K (grid 512). Swapped operands (A=w, B=z).
// All 4 waves share a per-row running max in LDS (thrS, float-as-uint,
// biased positive). Warm-up: chunk 0 scores -> atomicMax -> barrier, so the
// collecting loop starts with thr = max over 128 entries (collects ~2-4/row
// instead of ~15). Scores are bit-identical across warm-up and main loop
// (same MFMA sequence + C-init). Threshold only grows => every entry within
// EPS of the FINAL row max is always collected => true argmax always in the
// candidate set for ANY wave timing; fp64 rescore picks the deterministic
// exact winner.
__global__ __launch_bounds__(256, 2) void sweep_kernel(
    const float* __restrict__ z, const unsigned short* __restrict__ whi,
    const float* __restrict__ ncb, int* __restrict__ cnt,
    int* __restrict__ cand) {
  __shared__ unsigned int thrS[BMR];
  const int tid = threadIdx.x;
  const int n0  = (blockIdx.x >> 1) * BMR;
  const int khalf = blockIdx.x & 1;
  const int st  = blockIdx.x & 15;
  const int wv  = tid >> 6;
  const int ln  = tid & 63;
  const int g   = ln >> 4;
  const int lm  = ln & 15;
  const int estripe = wv * 32;

  if (tid < BMR) thrS[tid] = 0u;     // below any biased score (~[170,300])

  bf16x8 bz[8][2];
  #pragma unroll
  for (int rt = 0; rt < 8; ++rt) {
    const float* zr = z + (size_t)(n0 + rt * 16 + lm) * DIM;
    #pragma unroll
    for (int s = 0; s < 2; ++s) {
      float4 f0 = *(const float4*)(zr + s * 32 + g * 8);
      float4 f1 = *(const float4*)(zr + s * 32 + g * 8 + 4);
      float ff[8] = {f0.x, f0.y, f0.z, f0.w, f1.x, f1.y, f1.z, f1.w};
      bf16x8 h;
      #pragma unroll
      for (int i = 0; i < 8; ++i) h[i] = (short)f2bf(ff[i]);
      bz[rt][s] = h;
    }
  }
  __syncthreads();                   // thrS initialized

  bf16x8 awA[2][2], awB[2][2];
  f32x4  ncA[2], ncB[2];

  auto chunkbase = [&](int i) { return (khalf * 16 + ((i + st) & 15)) * BK; };
  auto loadW = [&](int kcb, bf16x8 (&aw)[2][2], f32x4 (&nc)[2]) {
    #pragma unroll
    for (int et = 0; et < 2; ++et) {
      const int ebase = kcb + estripe + et * 16;
      const unsigned short* wr = whi + (size_t)(ebase + lm) * DIM + g * 8;
      GLOAD(aw[et][0], wr);
      GLOAD(aw[et][1], wr + 32);
      GLOAD(nc[et], ncb + ebase + g * 4);
    }
  };
  auto mfma32 = [&](const bf16x8 (&aw)[2][2], const f32x4 (&nc)[2],
                    f32x4 (&acc)[2][8]) {
    #pragma unroll
    for (int et = 0; et < 2; ++et)
      #pragma unroll
      for (int rt = 0; rt < 8; ++rt)
        acc[et][rt] = (f32x4){nc[et][0], nc[et][1], nc[et][2], nc[et][3]};
    #pragma unroll
    for (int et = 0; et < 2; ++et)
      #pragma unroll
      for (int s = 0; s < 2; ++s)
        #pragma unroll
        for (int rt = 0; rt < 8; ++rt)
          acc[et][rt] = __builtin_amdgcn_mfma_f32_16x16x32_bf16(
              aw[et][s], bz[rt][s], acc[et][rt], 0, 0, 0);
  };
  auto chunkmax = [&](const f32x4 (&acc)[2][8], float (&cm)[8]) {
    #pragma unroll
    for (int rt = 0; rt < 8; ++rt)
      cm[rt] = fmaxf(
          fmaxf(fmaxf(acc[0][rt][0], acc[0][rt][1]),
                fmaxf(acc[0][rt][2], acc[0][rt][3])),
          fmaxf(fmaxf(acc[1][rt][0], acc[1][rt][1]),
                fmaxf(acc[1][rt][2], acc[1][rt][3])));
  };

  // ---- WARM-UP: chunk 0 max -> thrS (no collection) ----
  {
    loadW(chunkbase(0), awA, ncA);
    VMWAIT(0); SB0();
    f32x4 acc[2][8];
    mfma32(awA, ncA, acc);
    float cm[8];
    chunkmax(acc, cm);
    #pragma unroll
    for (int rt = 0; rt < 8; ++rt)
      atomicMax(&thrS[rt * 16 + lm], __float_as_uint(cm[rt]));
  }
  __syncthreads();                   // threshold warm across all 4 waves

  auto comp = [&](int kcb, const bf16x8 (&aw)[2][2], const f32x4 (&nc)[2]) {
    f32x4 acc[2][8];
    mfma32(aw, nc, acc);
    float cm[8];
    chunkmax(acc, cm);
    unsigned int oldv[8];
    #pragma unroll
    for (int rt = 0; rt < 8; ++rt)
      oldv[rt] = atomicMax(&thrS[rt * 16 + lm], __float_as_uint(cm[rt]));
    #pragma unroll
    for (int rt = 0; rt < 8; ++rt) {
      const float thr = fmaxf(__uint_as_float(oldv[rt]), cm[rt]) - EPS;
      if (__builtin_expect(cm[rt] >= thr, 0)) {
        const int rown = n0 + rt * 16 + lm;
        #pragma unroll
        for (int et = 0; et < 2; ++et)
          #pragma unroll
          for (int j = 0; j < 4; ++j) {
            if (acc[et][rt][j] >= thr) {
              int e = kcb + estripe + et * 16 + g * 4 + j;
              int p = atomicAdd(&cnt[rown], 1);
              if (p < CAPG) cand[rown * CAPG + p] = e;
            }
          }
      }
    }
  };

  loadW(chunkbase(0), awA, ncA);
  #pragma unroll 1
  for (int i = 0; i < 16; i += 2) {
    loadW(chunkbase(i + 1), awB, ncB);
    VMWAIT(6); SB0();
    comp(chunkbase(i), awA, ncA);
    if (i + 2 < 16) {
      loadW(chunkbase(i + 2), awA, ncA);
      VMWAIT(6);
    } else {
      VMWAIT(0);
    }
    SB0();
    comp(chunkbase(i + 1), awB, ncB);
  }
}

// Exact fp64 rescore (lane-per-candidate, CAPG<=64) + gather/loss/scatter.
__global__ __launch_bounds__(512) void rescore_gather_kernel(
    const float* __restrict__ z, const float* __restrict__ w,
    const int* __restrict__ cnt, const int* __restrict__ cand,
    float* __restrict__ out_idx, float* __restrict__ out_zq,
    float* __restrict__ out_loss, float* __restrict__ enc,
    float* __restrict__ emb) {
  const int bs = blockIdx.x;
  const int tid = threadIdx.x;
  const int h = tid >> 6, d = tid & 63;
  const int n = bs * 8 + h;

  int nn = cnt[n];
  double bl = -1.0e300;
  int wl = 0x7fffffff;
  if (nn <= CAPG) {
    if (d < nn) {                       // lane d rescores candidate d
      int c = cand[n * CAPG + d];
      double td = 0.0, ud = 0.0;
      #pragma unroll 8
      for (int d2 = 0; d2 < DIM; ++d2) {
        double wv = (double)w[(size_t)c * DIM + d2];
        double zv = (double)z[(size_t)n * DIM + d2];
        td = fma(zv, wv, td);
        ud = fma(wv, wv, ud);
      }
      bl = 2.0 * td - ud;
      wl = c;
    }
  } else {                              // overflow: full exact scan (rare)
    for (int t = 0; t < 64; ++t) {
      int c = t * 64 + d;
      double td = 0.0, ud = 0.0;
      for (int d2 = 0; d2 < DIM; ++d2) {
        double wv = (double)w[(size_t)c * DIM + d2];
        double zv = (double)z[(size_t)n * DIM + d2];
        td = fma(zv, wv, td);
        ud = fma(wv, wv, ud);
      }
      double sd = 2.0 * td - ud;
      if (sd > bl || (sd == bl && c < wl)) { bl = sd; wl = c; }
    }
  }
  #pragma unroll
  for (int mk = 1; mk <= 32; mk <<= 1) {
    double os = __shfl_xor(bl, mk);
    int   oi = __shfl_xor(wl, mk);
    if (os > bl || (os == bl && oi < wl)) { bl = os; wl = oi; }
  }
  int k = wl;
  k = (k < 0) ? 0 : ((k > K_ENT - 1) ? (K_ENT - 1) : k);  // safety clamp
  if (d == 0) out_idx[n] = (float)k;

  const float zf = z[(size_t)n * DIM + d];
  float wvf = w[(size_t)k * DIM + d];
  float stv = zf + (wvf - zf);              // straight-through, ref fp order
  out_zq[(size_t)n * DIM + d] = stv;
  float diff = zf - wvf;
  float s = diff * diff;
  #pragma unroll
  for (int mm = 32; mm >= 1; mm >>= 1) s += __shfl_down(s, mm, 64);
  __shared__ float red[8];
  if ((tid & 63) == 0) red[tid >> 6] = s;
  __syncthreads();
  if (tid == 0) {
    float t = 0.f;
    #pragma unroll
    for (int i = 0; i < 8; ++i) t += red[i];
    out_loss[bs] = t * (1.0f / 512.0f);
  }
  atomicAdd(&emb[(size_t)k * DIM + d], zf);
  if (d == 0) atomicAdd(&enc[k], 1.0f);
}

extern "C" void kernel_launch(void* const* d_in, const int* in_sizes, int n_in,
                              void* d_out, int out_size, void* d_ws, size_t ws_size,
                              hipStream_t stream) {
  const float* z = (const float*)d_in[0];
  const float* w = (const float*)d_in[1];
  float* ws  = (float*)d_ws;
  float* ncb = ws + WS_NCB;
  unsigned short* whi = (unsigned short*)(ws + WS_WHI);
  int* cnt  = (int*)(ws + WS_CNT);
  int* cand = (int*)(ws + WS_CAND);
  float* out = (float*)d_out;

  hipMemsetAsync(out + OUT_ENC, 0, (size_t)(4096 + 262144) * sizeof(float),
                 stream);
  hipMemsetAsync(cnt, 0, (size_t)N_TOTAL * sizeof(int), stream);

  prep_kernel<<<(K_ENT * DIM / 4) / 256, 256, 0, stream>>>(w, whi, ncb);
  sweep_kernel<<<(N_TOTAL / BMR) * 2, 256, 0, stream>>>(z, whi, ncb, cnt,
                                                        cand);
  rescore_gather_kernel<<<N_TOTAL / 8, 512, 0, stream>>>(
      z, w, cnt, cand, out + OUT_IDX, out + OUT_ZQ, out + OUT_LOSS,
      out + OUT_ENC, out + OUT_EMB);
}